// Round 6
// baseline (250.405 us; speedup 1.0000x reference)
//
#include <hip/hip_runtime.h>

// SNN membrane scan + spike + double-cumsum, single fused pipeline kernel.
//
// 256 blocks x 704 threads (11 waves), 1 block/CU. Per block: 64 channels.
// Roles: wave 0  = scan   (exact sequential membrane recurrence from LDS,
//                          bulk 32-t register window -> chain off LDS latency)
//        wave 1  = loader (cur  -> LDS ring via global_load_lds, 16 B/lane)
//        wave 2  = loader (vth  -> LDS ring via global_load_lds)
//        waves 3-10 = writers (replay spike bitmask + carry snapshot from LDS
//                              with exact int math; stream float4 stores)
// Pipeline over 32 segments of 32 timesteps (= 1 bit-dword each):
//   iter s: loaders fetch seg s+1 | scan consumes seg s, publishes bits+carry
//         | writers expand seg s-1 -> gz/zo.  One __syncthreads per iter.
// Reads of s+1 overlap writes of s-1 on every CU -> mixed R+W HBM streams.
//
// fmaf order + integer cumsums identical to prior passing kernels -> bit-exact.

#define T_LEN 1024
#define N_IN  512
#define BN    16384          // BATCH * N_IN
#define SEG_T 32             // timesteps per segment (= one bit-dword)
#define NSEG  (T_LEN / SEG_T)

// ---------------- global->LDS direct copy (16 B per lane, linear dest) ------
__device__ __forceinline__ void gload_lds16(const float* g, float* l) {
    __builtin_amdgcn_global_load_lds(
        (const __attribute__((address_space(1))) void*)g,
        (__attribute__((address_space(3))) void*)l, 16, 0, 0);
}

// Issue one 32-t segment of one array: 8 wave-instructions x 1 KB.
// Lane l covers t-row 4j + (l>>4), channels 4*(l&15)..+3.
// LDS layout: [t][ch] float, row stride 64 floats (256 B) -- linear dest.
__device__ __forceinline__ void issue_seg(const float* __restrict__ src,
                                          float* dst, int s, size_t goff) {
#pragma unroll
    for (int j = 0; j < SEG_T / 4; ++j) {
        gload_lds16(src + (size_t)(SEG_T * s + 4 * j) * BN + goff, dst + j * 256);
    }
}

__global__ __launch_bounds__(704, 1) void snn_fused(
        const float* __restrict__ cur, const float* __restrict__ beta,
        const float* __restrict__ vini, const float* __restrict__ vth,
        float* __restrict__ gz, float* __restrict__ zo, float* __restrict__ ml)
{
    __shared__ float    ldsC[2][SEG_T * 64];   // 2 x 8 KB  cur ring
    __shared__ float    ldsV[2][SEG_T * 64];   // 2 x 8 KB  vth ring
    __shared__ unsigned bitsb[2][64];          // spike bitmask per dword
    __shared__ unsigned pcb[2][64];            // packed carry C | Z<<11 (33 KB tot)

    const int lane   = threadIdx.x & 63;
    const int wave   = threadIdx.x >> 6;       // 0 scan, 1/2 loaders, 3..10 writers
    const int chbase = blockIdx.x * 64;
    const size_t goff = (size_t)chbase + (size_t)(lane >> 4) * BN
                      + (size_t)(4 * (lane & 15));

    // scan state (wave 0 only)
    float bta = 0.0f, m = 0.0f;
    int C = 0, Z = 0;
    if (wave == 0) {
        bta = beta[(chbase + lane) & (N_IN - 1)];
        m   = vini[chbase + lane];
    }

    // writer constants (waves 3..10)
    const int ww      = wave - 3;              // 0..7: writer wave id
    const int row_sub = lane >> 4;             // 0..3
    const int chgrp   = lane & 15;             // 0..15 -> channels 4*chgrp..+3
    const int myrow   = 4 * ww + row_sub;      // my t-row within the dword

    if (wave == 1) issue_seg(cur, &ldsC[0][0], 0, goff);
    if (wave == 2) issue_seg(vth, &ldsV[0][0], 0, goff);
    __syncthreads();                           // publishes segment 0

    for (int s = 0; s <= NSEG; ++s) {
        // ---- loaders: prefetch segment s+1 (consumed at iter s+1) ----------
        if (wave == 1 && s + 1 < NSEG) issue_seg(cur, &ldsC[(s + 1) & 1][0], s + 1, goff);
        if (wave == 2 && s + 1 < NSEG) issue_seg(vth, &ldsV[(s + 1) & 1][0], s + 1, goff);

        // ---- scan: consume segment s, publish bits + carry snapshot --------
        if (wave == 0 && s < NSEG) {
            const int cb = s & 1;
            pcb[cb][lane] = (unsigned)C | ((unsigned)Z << 11);   // state BEFORE seg
            const float* lc = &ldsC[cb][lane];
            const float* lv = &ldsV[cb][lane];
            float cc[SEG_T], vv[SEG_T];
#pragma unroll
            for (int t = 0; t < SEG_T; ++t) {   // bulk window: regs, static idx
                cc[t] = lc[t * 64];
                vv[t] = lv[t * 64];
            }
            unsigned mask = 0u;
#pragma unroll
            for (int t = 0; t < SEG_T; ++t) {
                m = fmaf(bta, m, cc[t]);              // exact same op/order
                const int sp = (m >= vv[t]) ? 1 : 0;  // Heaviside(m - vth)
                mask |= (unsigned)sp << t;
                C += sp;                              // c1 cumsum (exact int)
                Z += C;                               // z double-cumsum (exact)
            }
            bitsb[cb][lane] = mask;
            if (s == NSEG - 1) ml[chbase + lane] = m; // m_last (B,N)
        }

        // ---- writers: expand dword s-1 -> gz/zo ----------------------------
        if (wave >= 3 && s >= 1) {
            const int ds = s - 1;
            const int pb = ds & 1;
            const uint4 ub = *reinterpret_cast<const uint4*>(&bitsb[pb][4 * chgrp]);
            const uint4 pp = *reinterpret_cast<const uint4*>(&pcb[pb][4 * chgrp]);
            int C0 = (int)(pp.x & 0x7FFu), Z0 = (int)(pp.x >> 11);
            int C1 = (int)(pp.y & 0x7FFu), Z1 = (int)(pp.y >> 11);
            int C2 = (int)(pp.z & 0x7FFu), Z2 = (int)(pp.z >> 11);
            int C3 = (int)(pp.w & 0x7FFu), Z3 = (int)(pp.w >> 11);
            int zq0 = 0, zq1 = 0, zq2 = 0, zq3 = 0;
            const int tmax = 4 * ww + 4;               // wave-uniform trip count
            for (int t = 0; t < tmax; ++t) {           // exact integer replay
                C0 += (int)((ub.x >> t) & 1u); Z0 += C0;
                C1 += (int)((ub.y >> t) & 1u); Z1 += C1;
                C2 += (int)((ub.z >> t) & 1u); Z2 += C2;
                C3 += (int)((ub.w >> t) & 1u); Z3 += C3;
                zq0 = (t == myrow) ? Z0 : zq0;         // predicated capture
                zq1 = (t == myrow) ? Z1 : zq1;
                zq2 = (t == myrow) ? Z2 : zq2;
                zq3 = (t == myrow) ? Z3 : zq3;
            }
            const size_t off = (size_t)(ds * 32 + myrow) * BN + chbase + 4 * chgrp;
            const float4 gf = make_float4(zq0 == 1 ? 1.0f : 0.0f,
                                          zq1 == 1 ? 1.0f : 0.0f,
                                          zq2 == 1 ? 1.0f : 0.0f,
                                          zq3 == 1 ? 1.0f : 0.0f);
            const float4 zf = make_float4((float)zq0, (float)zq1,
                                          (float)zq2, (float)zq3);
            *reinterpret_cast<float4*>(gz + off) = gf;   // Block.g forward value
            *reinterpret_cast<float4*>(zo + off) = zf;   // exact: z < 2^21
        }

        if (s < NSEG) __syncthreads();   // publish s+1 / release buffers
    }
}

extern "C" void kernel_launch(void* const* d_in, const int* in_sizes, int n_in,
                              void* d_out, int out_size, void* d_ws, size_t ws_size,
                              hipStream_t stream) {
    const float* cur  = (const float*)d_in[0];   // (T,B,N) fp32
    const float* beta = (const float*)d_in[1];   // (N,)
    const float* vini = (const float*)d_in[2];   // (B,N)
    const float* vth  = (const float*)d_in[3];   // (T,B,N)
    float* gz = (float*)d_out;                       // (T,B,N)
    float* zo = gz + (size_t)T_LEN * BN;             // (T,B,N)
    float* ml = zo + (size_t)T_LEN * BN;             // (B,N)

    snn_fused<<<BN / 64, 704, 0, stream>>>(cur, beta, vini, vth, gz, zo, ml);
}

// Round 7
// 241.063 us; speedup vs baseline: 1.0388x; 1.0388x over previous
//
#include <hip/hip_runtime.h>

// SNN membrane scan + spike + double-cumsum, single fused pipeline kernel.
//
// 256 blocks x 704 threads (11 waves), 1 block/CU. Per block: 64 channels.
// Roles: wave 0  = scan   (exact sequential membrane recurrence from LDS;
//                          publishes float(Z) PER TIMESTEP -> no consumer replay)
//        wave 1  = loader (cur -> LDS ring via global_load_lds, 16 B/lane)
//        wave 2  = loader (vth -> LDS ring via global_load_lds)
//        waves 3-10 = writers (1 ds_read_b128 + compare + 2 float4 stores each;
//                              zero integer replay)
// Pipeline over 32 segments of 32 timesteps:
//   iter s: loaders fetch seg s+1 | scan consumes seg s, publishes Z[t] to LDS
//         | writers store seg s-1 -> gz/zo.  One __syncthreads per iter.
//
// fmaf order + integer cumsums identical to prior passing kernels -> bit-exact.
// gz test (Z==1) done on float: Z < 2^21 is exact in fp32.

#define T_LEN 1024
#define N_IN  512
#define BN    16384          // BATCH * N_IN
#define SEG_T 32             // timesteps per segment
#define NSEG  (T_LEN / SEG_T)

// ---------------- global->LDS direct copy (16 B per lane, linear dest) ------
__device__ __forceinline__ void gload_lds16(const float* g, float* l) {
    __builtin_amdgcn_global_load_lds(
        (const __attribute__((address_space(1))) void*)g,
        (__attribute__((address_space(3))) void*)l, 16, 0, 0);
}

// Issue one 32-t segment of one array: 8 wave-instructions x 1 KB.
// Lane l covers t-row 4j + (l>>4), channels 4*(l&15)..+3.
// LDS layout: [t][ch] float, row stride 64 floats (256 B) -- linear dest.
__device__ __forceinline__ void issue_seg(const float* __restrict__ src,
                                          float* dst, int s, size_t goff) {
#pragma unroll
    for (int j = 0; j < SEG_T / 4; ++j) {
        gload_lds16(src + (size_t)(SEG_T * s + 4 * j) * BN + goff, dst + j * 256);
    }
}

__global__ __launch_bounds__(704, 1) void snn_fused(
        const float* __restrict__ cur, const float* __restrict__ beta,
        const float* __restrict__ vini, const float* __restrict__ vth,
        float* __restrict__ gz, float* __restrict__ zo, float* __restrict__ ml)
{
    __shared__ float ldsC[2][SEG_T * 64];   // 2 x 8 KB  cur ring
    __shared__ float ldsV[2][SEG_T * 64];   // 2 x 8 KB  vth ring
    __shared__ float zbuf[2][SEG_T][64];    // 2 x 8 KB  float(Z) per t per ch

    const int lane   = threadIdx.x & 63;
    const int wave   = threadIdx.x >> 6;    // 0 scan, 1/2 loaders, 3..10 writers
    const int chbase = blockIdx.x * 64;
    const size_t goff = (size_t)chbase + (size_t)(lane >> 4) * BN
                      + (size_t)(4 * (lane & 15));

    // scan state (wave 0 only)
    float bta = 0.0f, m = 0.0f;
    int C = 0, Z = 0;
    if (wave == 0) {
        bta = beta[(chbase + lane) & (N_IN - 1)];
        m   = vini[chbase + lane];
    }

    // writer constants (waves 3..10): each lane owns one t-row x 4 channels
    const int ww      = wave - 3;           // 0..7: writer wave id
    const int row_sub = lane >> 4;          // 0..3
    const int chgrp   = lane & 15;          // 0..15 -> channels 4*chgrp..+3
    const int myrow   = 4 * ww + row_sub;   // my t-row within the segment

    if (wave == 1) issue_seg(cur, &ldsC[0][0], 0, goff);
    if (wave == 2) issue_seg(vth, &ldsV[0][0], 0, goff);
    __syncthreads();                        // publishes segment 0

    for (int s = 0; s <= NSEG; ++s) {
        // ---- loaders: prefetch segment s+1 (consumed at iter s+1) ----------
        if (wave == 1 && s + 1 < NSEG) issue_seg(cur, &ldsC[(s + 1) & 1][0], s + 1, goff);
        if (wave == 2 && s + 1 < NSEG) issue_seg(vth, &ldsV[(s + 1) & 1][0], s + 1, goff);

        // ---- scan: consume segment s, publish float(Z) per timestep --------
        if (wave == 0 && s < NSEG) {
            const int cb = s & 1;
            const float* lc = &ldsC[cb][lane];
            const float* lv = &ldsV[cb][lane];
            float cc[SEG_T], vv[SEG_T];
#pragma unroll
            for (int t = 0; t < SEG_T; ++t) {   // bulk window: regs, static idx
                cc[t] = lc[t * 64];
                vv[t] = lv[t * 64];
            }
#pragma unroll
            for (int t = 0; t < SEG_T; ++t) {
                m = fmaf(bta, m, cc[t]);              // exact same op/order
                const int sp = (m >= vv[t]) ? 1 : 0;  // Heaviside(m - vth)
                C += sp;                              // c1 cumsum (exact int)
                Z += C;                               // z double-cumsum (exact)
                zbuf[cb][t][lane] = (float)Z;         // off-chain publish
            }
            if (s == NSEG - 1) ml[chbase + lane] = m; // m_last (B,N)
        }

        // ---- writers: store segment s-1 -> gz/zo (no replay) ---------------
        if (wave >= 3 && s >= 1) {
            const int ds_ = s - 1;
            const int pb = ds_ & 1;
            const float4 zq = *reinterpret_cast<const float4*>(
                                  &zbuf[pb][myrow][4 * chgrp]);
            const float4 gf = make_float4(zq.x == 1.0f ? 1.0f : 0.0f,
                                          zq.y == 1.0f ? 1.0f : 0.0f,
                                          zq.z == 1.0f ? 1.0f : 0.0f,
                                          zq.w == 1.0f ? 1.0f : 0.0f);
            const size_t off = (size_t)(ds_ * 32 + myrow) * BN
                             + chbase + 4 * chgrp;
            *reinterpret_cast<float4*>(gz + off) = gf;   // Block.g forward value
            *reinterpret_cast<float4*>(zo + off) = zq;   // exact: z < 2^21
        }

        if (s < NSEG) __syncthreads();   // publish s+1 / release buffers
    }
}

extern "C" void kernel_launch(void* const* d_in, const int* in_sizes, int n_in,
                              void* d_out, int out_size, void* d_ws, size_t ws_size,
                              hipStream_t stream) {
    const float* cur  = (const float*)d_in[0];   // (T,B,N) fp32
    const float* beta = (const float*)d_in[1];   // (N,)
    const float* vini = (const float*)d_in[2];   // (B,N)
    const float* vth  = (const float*)d_in[3];   // (T,B,N)
    float* gz = (float*)d_out;                       // (T,B,N)
    float* zo = gz + (size_t)T_LEN * BN;             // (T,B,N)
    float* ml = zo + (size_t)T_LEN * BN;             // (B,N)

    snn_fused<<<BN / 64, 704, 0, stream>>>(cur, beta, vini, vth, gz, zo, ml);
}